// Round 1
// baseline (457.914 us; speedup 1.0000x reference)
//
#include <hip/hip_runtime.h>
#include <hip/hip_bf16.h>
#include <cstddef>

// Problem constants
// B=4, N=512, FD=256, AD=256, PD=128, DP=64
// out[b,q] = softmax_k( (Q[b,q]·K[b,k] + bias[b,q,k]) / 16 ) · vsum[b,k]
//   bias[b,i,j] = rn*(dot(D[b,i,j,:],gw) - mu*sum_gw) + bconst
//   vsum[b,k]   = Fn[b,k,:]·rowsum(Wv)
//
// Workspace layout (floats):
#define OFF_GW    0          // 64   : g_p * (W_pt @ W_ph)
#define OFF_WV    64         // 256  : row sums of Wv
#define OFF_SC    320        // 2    : sum_gw, bconst
#define OFF_VSUM  384        // 2048 : vsum[b,k]
#define OFF_Q     2432       // 524288 : Q [2048][256]
#define OFF_K     526720     // 524288 : K [2048][256]
#define OFF_SB    1051008    // 1048576 : bias/16  [4][512][512]
// total ~8.4 MB of d_ws

// ---------------- K0: constants -------------------------------------------
__global__ __launch_bounds__(256) void k0_consts(
    const float* __restrict__ Wv, const float* __restrict__ g_p,
    const float* __restrict__ b_p, const float* __restrict__ W_pt,
    const float* __restrict__ b_pt, const float* __restrict__ W_ph,
    float* __restrict__ ws) {
  int t = threadIdx.x;
  if (blockIdx.x < 64) {
    // wv_sum: 4 rows of Wv per block, one wave per row (coalesced)
    int row = blockIdx.x * 4 + (t >> 6);
    int l = t & 63;
    float s = 0.f;
#pragma unroll
    for (int j = 0; j < 4; ++j) s += Wv[row * 256 + l + 64 * j];
    for (int m = 32; m >= 1; m >>= 1) s += __shfl_xor(s, m);
    if (l == 0) ws[OFF_WV + row] = s;
  } else {
    __shared__ float wc_s[64];
    __shared__ float wph_s[128];
    if (t < 128) wph_s[t] = W_ph[t];
    __syncthreads();
    int c = t >> 2, sub = t & 3;  // 4 lanes per channel c
    float wc = 0.f;
#pragma unroll
    for (int j = 0; j < 32; ++j)
      wc += W_pt[c * 128 + sub * 32 + j] * wph_s[sub * 32 + j];
    wc += __shfl_xor(wc, 1);
    wc += __shfl_xor(wc, 2);
    if (sub == 0) {
      wc_s[c] = wc;
      ws[OFF_GW + c] = g_p[c] * wc;
    }
    __syncthreads();
    if (t == 0) {
      float sg = 0.f, bc = 0.f;
      for (int cc = 0; cc < 64; ++cc) {
        sg += g_p[cc] * wc_s[cc];
        bc += b_p[cc] * wc_s[cc];
      }
      for (int p = 0; p < 128; ++p) bc += b_pt[p] * wph_s[p];
      ws[OFF_SC] = sg;
      ws[OFF_SC + 1] = bc;
    }
  }
}

// ---------------- K1: LN(F) + Q,K projection + vsum ------------------------
// 8 rows per block, 256 threads. Wq/Wk read coalesced, L2-amortized.
__global__ __launch_bounds__(256) void k1_ln_qk(
    const float* __restrict__ F, const float* __restrict__ Wq,
    const float* __restrict__ Wk, const float* __restrict__ g_f,
    const float* __restrict__ b_f, float* __restrict__ ws) {
  __shared__ float fn[8][257];
  __shared__ float smu[8], srn[8];
  int t = threadIdx.x;
  int row0 = blockIdx.x * 8;  // global row in [0,2048)
  const float* Fp = F + (size_t)row0 * 256;
#pragma unroll
  for (int k = 0; k < 8; ++k) fn[k][t] = Fp[k * 256 + t];
  __syncthreads();
  // stats: 32 threads per row
  int r = t >> 5, l32 = t & 31;
  float s1 = 0.f, s2 = 0.f;
#pragma unroll
  for (int m = 0; m < 8; ++m) {
    float x = fn[r][l32 + 32 * m];
    s1 += x;
    s2 += x * x;
  }
  for (int m = 16; m >= 1; m >>= 1) {
    s1 += __shfl_xor(s1, m);
    s2 += __shfl_xor(s2, m);
  }
  if (l32 == 0) {
    float mu = s1 * (1.f / 256.f);
    float var = s2 * (1.f / 256.f) - mu * mu;
    smu[r] = mu;
    srn[r] = rsqrtf(var + 1e-3f);
  }
  __syncthreads();
  // normalize (thread t owns column t of all 8 rows)
  float gf = g_f[t], bf = b_f[t];
#pragma unroll
  for (int k = 0; k < 8; ++k)
    fn[k][t] = (fn[k][t] - smu[k]) * srn[k] * gf + bf;
  __syncthreads();
  // vsum
  {
    const float* wv = ws + OFF_WV;
    float s = 0.f;
#pragma unroll
    for (int m = 0; m < 8; ++m) s += fn[r][l32 + 32 * m] * wv[l32 + 32 * m];
    for (int m = 16; m >= 1; m >>= 1) s += __shfl_xor(s, m);
    if (l32 == 0) ws[OFF_VSUM + row0 + r] = s;
  }
  // Q/K: thread t computes output column t for all 8 rows
  float qa[8] = {0, 0, 0, 0, 0, 0, 0, 0};
  float ka[8] = {0, 0, 0, 0, 0, 0, 0, 0};
  for (int f = 0; f < 256; ++f) {
    float wq = Wq[f * 256 + t];
    float wk = Wk[f * 256 + t];
#pragma unroll
    for (int k = 0; k < 8; ++k) {
      float x = fn[k][f];  // wave-uniform LDS broadcast
      qa[k] += x * wq;
      ka[k] += x * wk;
    }
  }
  float* Qo = ws + OFF_Q + (size_t)row0 * 256;
  float* Ko = ws + OFF_K + (size_t)row0 * 256;
#pragma unroll
  for (int k = 0; k < 8; ++k) {
    Qo[k * 256 + t] = qa[k];
    Ko[k * 256 + t] = ka[k];
  }
}

// ---------------- K2: pair-bias over D (HBM-bound, 268 MB) -----------------
// 4 lanes per entry (64 floats); quad shuffle-reduce; writes bias/16.
__global__ __launch_bounds__(256) void k2_bias(const float* __restrict__ D,
                                               float* __restrict__ ws) {
  int tid = blockIdx.x * 256 + threadIdx.x;
  int e = tid >> 2;  // entry in [0, 4*512*512)
  int q = tid & 3;   // quarter of the 64-float row
  const float4* dp = (const float4*)(D + (size_t)e * 64 + q * 16);
  const float4* gw4 = (const float4*)(ws + OFF_GW) + q * 4;
  float s1 = 0.f, s2 = 0.f, sw = 0.f;
#pragma unroll
  for (int j = 0; j < 4; ++j) {
    float4 x = dp[j];
    float4 g = gw4[j];
    s1 += x.x + x.y + x.z + x.w;
    s2 += x.x * x.x + x.y * x.y + x.z * x.z + x.w * x.w;
    sw += x.x * g.x + x.y * g.y + x.z * g.z + x.w * g.w;
  }
  s1 += __shfl_xor(s1, 1);
  s2 += __shfl_xor(s2, 1);
  sw += __shfl_xor(sw, 1);
  s1 += __shfl_xor(s1, 2);
  s2 += __shfl_xor(s2, 2);
  sw += __shfl_xor(sw, 2);
  if (q == 0) {
    float mu = s1 * (1.f / 64.f);
    float var = s2 * (1.f / 64.f) - mu * mu;
    float rn = rsqrtf(var + 1e-3f);
    float sum_gw = ws[OFF_SC];
    float bconst = ws[OFF_SC + 1];
    ws[OFF_SB + e] = (rn * (sw - mu * sum_gw) + bconst) * 0.0625f;
  }
}

// ---------------- K3: QK^T/16 + bias, softmax, ·vsum -----------------------
// 4 q-rows per block (512 blocks = 2/CU). Thread t owns k-cols t and t+256.
__global__ __launch_bounds__(256) void k3_attn(const float* __restrict__ ws,
                                               float* __restrict__ out) {
  __shared__ float4 Qs4[4][64];
  __shared__ float Sx[4][512];
  __shared__ float vs[512];
  int t = threadIdx.x;
  int b = blockIdx.x >> 7;      // 128 tiles per batch
  int tile = blockIdx.x & 127;
  int q0 = tile * 4;
  int rowbase = b * 512 + q0;   // global q row
  const float* Qg = ws + OFF_Q;
  const float* Kg = ws + OFF_K;
  float* qsf = (float*)Qs4;
#pragma unroll
  for (int k = 0; k < 4; ++k) qsf[k * 256 + t] = Qg[(size_t)(rowbase + k) * 256 + t];
  vs[t] = ws[OFF_VSUM + b * 512 + t];
  vs[t + 256] = ws[OFF_VSUM + b * 512 + 256 + t];
  __syncthreads();
  const float4* K0p = (const float4*)(Kg + (size_t)(b * 512 + t) * 256);
  const float4* K1p = (const float4*)(Kg + (size_t)(b * 512 + 256 + t) * 256);
  float a0[4] = {0, 0, 0, 0}, a1[4] = {0, 0, 0, 0};
  for (int f = 0; f < 64; ++f) {
    float4 kv0 = K0p[f];
    float4 kv1 = K1p[f];
#pragma unroll
    for (int rr = 0; rr < 4; ++rr) {
      float4 qv = Qs4[rr][f];  // wave-uniform broadcast
      a0[rr] += qv.x * kv0.x + qv.y * kv0.y + qv.z * kv0.z + qv.w * kv0.w;
      a1[rr] += qv.x * kv1.x + qv.y * kv1.y + qv.z * kv1.z + qv.w * kv1.w;
    }
  }
  const float* sb = ws + OFF_SB;
#pragma unroll
  for (int rr = 0; rr < 4; ++rr) {
    size_t sbrow = (size_t)(rowbase + rr) * 512;
    Sx[rr][t] = a0[rr] * 0.0625f + sb[sbrow + t];
    Sx[rr][t + 256] = a1[rr] * 0.0625f + sb[sbrow + 256 + t];
  }
  __syncthreads();
  // wave w handles row w
  int w = t >> 6, l = t & 63;
  float m = -1e30f;
#pragma unroll
  for (int j = 0; j < 8; ++j) m = fmaxf(m, Sx[w][l + 64 * j]);
  for (int mm = 32; mm >= 1; mm >>= 1) m = fmaxf(m, __shfl_xor(m, mm));
  float se = 0.f, sv = 0.f;
#pragma unroll
  for (int j = 0; j < 8; ++j) {
    float ev = __expf(Sx[w][l + 64 * j] - m);
    se += ev;
    sv += ev * vs[l + 64 * j];
  }
  for (int mm = 32; mm >= 1; mm >>= 1) {
    se += __shfl_xor(se, mm);
    sv += __shfl_xor(sv, mm);
  }
  if (l == 0) out[rowbase + w] = sv / se;
}

// ---------------------------------------------------------------------------
extern "C" void kernel_launch(void* const* d_in, const int* in_sizes, int n_in,
                              void* d_out, int out_size, void* d_ws,
                              size_t ws_size, hipStream_t stream) {
  const float* F    = (const float*)d_in[0];
  const float* D    = (const float*)d_in[1];
  const float* Wq   = (const float*)d_in[2];
  const float* Wk   = (const float*)d_in[3];
  const float* Wv   = (const float*)d_in[4];
  const float* g_f  = (const float*)d_in[5];
  const float* b_f  = (const float*)d_in[6];
  const float* g_p  = (const float*)d_in[7];
  const float* b_p  = (const float*)d_in[8];
  const float* W_pt = (const float*)d_in[9];
  const float* b_pt = (const float*)d_in[10];
  const float* W_ph = (const float*)d_in[11];
  float* out = (float*)d_out;
  float* ws = (float*)d_ws;

  k0_consts<<<65, 256, 0, stream>>>(Wv, g_p, b_p, W_pt, b_pt, W_ph, ws);
  k1_ln_qk<<<256, 256, 0, stream>>>(F, Wq, Wk, g_f, b_f, ws);
  // 4*512*512 entries * 4 lanes / 256 threads = 16384 blocks
  k2_bias<<<16384, 256, 0, stream>>>(D, ws);
  k3_attn<<<512, 256, 0, stream>>>(ws, out);
}

// Round 2
// 450.928 us; speedup vs baseline: 1.0155x; 1.0155x over previous
//
#include <hip/hip_runtime.h>
#include <hip/hip_bf16.h>
#include <cstddef>

// Problem constants: B=4, N=512, FD=AD=256, PD=128, DP=64
// out[b,q] = softmax_k( (Q[b,q]·K[b,k] + bias[b,q,k]) / 16 ) · vsum[b,k]
//   bias[b,i,j] = rn*(dot(D[b,i,j,:],gw) - mu*sum_gw) + bconst   (gw = g_p*(W_pt@W_ph))
//   vsum[b,k]   = Fn[b,k,:]·rowsum(Wv)
//
// Workspace layout (floats):
#define OFF_GW    0          // 64   : g_p * (W_pt @ W_ph)
#define OFF_WV    64         // 256  : row sums of Wv
#define OFF_SC    320        // 2    : sum_gw, bconst
#define OFF_VSUM  384        // 2048 : vsum[b,k]
#define OFF_Q     2432       // 524288 : Q [2048][256]
#define OFF_K     526720     // 524288 : K [2048][256]
// total ~4.2 MB of d_ws

// ---------------- K0: constants -------------------------------------------
__global__ __launch_bounds__(256) void k0_consts(
    const float* __restrict__ Wv, const float* __restrict__ g_p,
    const float* __restrict__ b_p, const float* __restrict__ W_pt,
    const float* __restrict__ b_pt, const float* __restrict__ W_ph,
    float* __restrict__ ws) {
  int t = threadIdx.x;
  if (blockIdx.x < 64) {
    // wv_sum: 4 rows of Wv per block, one wave per row (coalesced)
    int row = blockIdx.x * 4 + (t >> 6);
    int l = t & 63;
    float s = 0.f;
#pragma unroll
    for (int j = 0; j < 4; ++j) s += Wv[row * 256 + l + 64 * j];
    for (int m = 32; m >= 1; m >>= 1) s += __shfl_xor(s, m);
    if (l == 0) ws[OFF_WV + row] = s;
  } else {
    __shared__ float wc_s[64];
    __shared__ float wph_s[128];
    if (t < 128) wph_s[t] = W_ph[t];
    __syncthreads();
    int c = t >> 2, sub = t & 3;  // 4 lanes per channel c
    float wc = 0.f;
#pragma unroll
    for (int j = 0; j < 32; ++j)
      wc += W_pt[c * 128 + sub * 32 + j] * wph_s[sub * 32 + j];
    wc += __shfl_xor(wc, 1);
    wc += __shfl_xor(wc, 2);
    if (sub == 0) {
      wc_s[c] = wc;
      ws[OFF_GW + c] = g_p[c] * wc;
    }
    __syncthreads();
    if (t == 0) {
      float sg = 0.f, bc = 0.f;
      for (int cc = 0; cc < 64; ++cc) {
        sg += g_p[cc] * wc_s[cc];
        bc += b_p[cc] * wc_s[cc];
      }
      for (int p = 0; p < 128; ++p) bc += b_pt[p] * wph_s[p];
      ws[OFF_SC] = sg;
      ws[OFF_SC + 1] = bc;
    }
  }
}

// ---------------- K1: LN(F) + Q,K projection + vsum ------------------------
// 512 blocks: rowgroup g = bid>>1 (8 rows), column half h = bid&1.
// Waves 0-1 compute Wq columns, waves 2-3 compute Wk columns.
__global__ __launch_bounds__(256) void k1_ln_qk(
    const float* __restrict__ F, const float* __restrict__ Wq,
    const float* __restrict__ Wk, const float* __restrict__ g_f,
    const float* __restrict__ b_f, float* __restrict__ ws) {
  __shared__ float fn[8][257];
  __shared__ float smu[8], srn[8];
  int t = threadIdx.x;
  int g = blockIdx.x >> 1, h = blockIdx.x & 1;
  int row0 = g * 8;  // global row in [0,2048)
  const float* Fp = F + (size_t)row0 * 256;
#pragma unroll
  for (int k = 0; k < 8; ++k) fn[k][t] = Fp[k * 256 + t];
  __syncthreads();
  // stats: 32 threads per row
  int r = t >> 5, l32 = t & 31;
  float s1 = 0.f, s2 = 0.f;
#pragma unroll
  for (int m = 0; m < 8; ++m) {
    float x = fn[r][l32 + 32 * m];
    s1 += x;
    s2 += x * x;
  }
  for (int m = 16; m >= 1; m >>= 1) {
    s1 += __shfl_xor(s1, m);
    s2 += __shfl_xor(s2, m);
  }
  if (l32 == 0) {
    float mu = s1 * (1.f / 256.f);
    float var = s2 * (1.f / 256.f) - mu * mu;
    smu[r] = mu;
    srn[r] = rsqrtf(var + 1e-3f);
  }
  __syncthreads();
  float gf = g_f[t], bf = b_f[t];
#pragma unroll
  for (int k = 0; k < 8; ++k)
    fn[k][t] = (fn[k][t] - smu[k]) * srn[k] * gf + bf;
  __syncthreads();
  if (h == 0) {  // vsum only once per row-group
    const float* wv = ws + OFF_WV;
    float s = 0.f;
#pragma unroll
    for (int m = 0; m < 8; ++m) s += fn[r][l32 + 32 * m] * wv[l32 + 32 * m];
    for (int m = 16; m >= 1; m >>= 1) s += __shfl_xor(s, m);
    if (l32 == 0) ws[OFF_VSUM + row0 + r] = s;
  }
  // projection: thread t -> matrix (t>>7), column h*128 + (t&127)
  int matsel = t >> 7;
  int col = h * 128 + (t & 127);
  const float* W = matsel ? Wk : Wq;
  float acc[8] = {0, 0, 0, 0, 0, 0, 0, 0};
#pragma unroll 4
  for (int f = 0; f < 256; ++f) {
    float w = W[f * 256 + col];
#pragma unroll
    for (int k = 0; k < 8; ++k) acc[k] += fn[k][f] * w;
  }
  float* Out = ws + (matsel ? OFF_K : OFF_Q) + (size_t)row0 * 256 + col;
#pragma unroll
  for (int k = 0; k < 8; ++k) Out[k * 256] = acc[k];
}

// ---------------- KB: fused pair-bias + QK^T + softmax + ·vsum -------------
// 512 blocks = (b, 4-q-row tile). Each block streams its own 512 KB of D
// (bias LN), adds QK^T/16, softmaxes per row, dots with vsum.
__global__ __launch_bounds__(256) void kb_bias_attn(
    const float* __restrict__ D, const float* __restrict__ ws,
    float* __restrict__ out) {
  __shared__ float4 Qs4[4][64];
  __shared__ float Sx[4][512];
  __shared__ float vs[512];
  int t = threadIdx.x;
  int b = blockIdx.x >> 7;      // 128 tiles per batch
  int tile = blockIdx.x & 127;
  int q0 = tile * 4;
  int rowbase = b * 512 + q0;   // global q row
  // stage Q rows + vsum
  float* qsf = (float*)Qs4;
#pragma unroll
  for (int k = 0; k < 4; ++k)
    qsf[k * 256 + t] = ws[OFF_Q + (size_t)(rowbase + k) * 256 + t];
  vs[t] = ws[OFF_VSUM + b * 512 + t];
  vs[t + 256] = ws[OFF_VSUM + b * 512 + 256 + t];
  float sum_gw = ws[OFF_SC];
  float bconst = ws[OFF_SC + 1];
  // this lane's quarter of gw (16 floats)
  int qq = t & 3;
  float4 g[4];
#pragma unroll
  for (int j = 0; j < 4; ++j) g[j] = ((const float4*)(ws + OFF_GW))[qq * 4 + j];

  // Phase A: bias for 4 q-rows x 512 k. 4 lanes per (q,k) entry; 32 passes.
  int e4 = t >> 2;  // 0..63
  const float* Dbase = D + (size_t)rowbase * 512 * 64;
#pragma unroll 4
  for (int pi = 0; pi < 32; ++pi) {
    int rr = pi >> 3;
    int kk = (pi & 7) * 64 + e4;
    const float4* dp =
        (const float4*)(Dbase + ((size_t)rr * 512 + kk) * 64 + qq * 16);
    float s1 = 0.f, s2 = 0.f, sw = 0.f;
#pragma unroll
    for (int j = 0; j < 4; ++j) {
      float4 x = dp[j];
      s1 += x.x + x.y + x.z + x.w;
      s2 += x.x * x.x + x.y * x.y + x.z * x.z + x.w * x.w;
      sw += x.x * g[j].x + x.y * g[j].y + x.z * g[j].z + x.w * g[j].w;
    }
    s1 += __shfl_xor(s1, 1);
    s2 += __shfl_xor(s2, 1);
    sw += __shfl_xor(sw, 1);
    s1 += __shfl_xor(s1, 2);
    s2 += __shfl_xor(s2, 2);
    sw += __shfl_xor(sw, 2);
    if (qq == 0) {
      float mu = s1 * (1.f / 64.f);
      float var = s2 * (1.f / 64.f) - mu * mu;
      float rn = rsqrtf(var + 1e-3f);
      Sx[rr][kk] = (rn * (sw - mu * sum_gw) + bconst) * 0.0625f;
    }
  }
  __syncthreads();

  // Phase B: QK^T/16 added into Sx. Thread t owns k-cols t and t+256.
  const float* Kg = ws + OFF_K;
  const float4* K0p = (const float4*)(Kg + (size_t)(b * 512 + t) * 256);
  const float4* K1p = (const float4*)(Kg + (size_t)(b * 512 + 256 + t) * 256);
  float a0[4] = {0, 0, 0, 0}, a1[4] = {0, 0, 0, 0};
#pragma unroll 4
  for (int f = 0; f < 64; ++f) {
    float4 kv0 = K0p[f];
    float4 kv1 = K1p[f];
#pragma unroll
    for (int rr = 0; rr < 4; ++rr) {
      float4 qv = Qs4[rr][f];  // wave-uniform LDS broadcast
      a0[rr] += qv.x * kv0.x + qv.y * kv0.y + qv.z * kv0.z + qv.w * kv0.w;
      a1[rr] += qv.x * kv1.x + qv.y * kv1.y + qv.z * kv1.z + qv.w * kv1.w;
    }
  }
#pragma unroll
  for (int rr = 0; rr < 4; ++rr) {
    Sx[rr][t] += a0[rr] * 0.0625f;
    Sx[rr][t + 256] += a1[rr] * 0.0625f;
  }
  __syncthreads();

  // Phase C: wave w softmaxes row w and dots with vsum
  int w = t >> 6, l = t & 63;
  float m = -1e30f;
#pragma unroll
  for (int j = 0; j < 8; ++j) m = fmaxf(m, Sx[w][l + 64 * j]);
  for (int mm = 32; mm >= 1; mm >>= 1) m = fmaxf(m, __shfl_xor(m, mm));
  float se = 0.f, sv = 0.f;
#pragma unroll
  for (int j = 0; j < 8; ++j) {
    float ev = __expf(Sx[w][l + 64 * j] - m);
    se += ev;
    sv += ev * vs[l + 64 * j];
  }
  for (int mm = 32; mm >= 1; mm >>= 1) {
    se += __shfl_xor(se, mm);
    sv += __shfl_xor(sv, mm);
  }
  if (l == 0) out[rowbase + w] = sv / se;
}

// ---------------------------------------------------------------------------
extern "C" void kernel_launch(void* const* d_in, const int* in_sizes, int n_in,
                              void* d_out, int out_size, void* d_ws,
                              size_t ws_size, hipStream_t stream) {
  const float* F    = (const float*)d_in[0];
  const float* D    = (const float*)d_in[1];
  const float* Wq   = (const float*)d_in[2];
  const float* Wk   = (const float*)d_in[3];
  const float* Wv   = (const float*)d_in[4];
  const float* g_f  = (const float*)d_in[5];
  const float* b_f  = (const float*)d_in[6];
  const float* g_p  = (const float*)d_in[7];
  const float* b_p  = (const float*)d_in[8];
  const float* W_pt = (const float*)d_in[9];
  const float* b_pt = (const float*)d_in[10];
  const float* W_ph = (const float*)d_in[11];
  float* out = (float*)d_out;
  float* ws = (float*)d_ws;

  k0_consts<<<65, 256, 0, stream>>>(Wv, g_p, b_p, W_pt, b_pt, W_ph, ws);
  k1_ln_qk<<<512, 256, 0, stream>>>(F, Wq, Wk, g_f, b_f, ws);
  kb_bias_attn<<<512, 256, 0, stream>>>(D, ws, out);
}

// Round 3
// 441.929 us; speedup vs baseline: 1.0362x; 1.0204x over previous
//
#include <hip/hip_runtime.h>
#include <hip/hip_bf16.h>
#include <cstddef>

// Problem constants: B=4, N=512, FD=AD=256, PD=128, DP=64
// out[b,q] = softmax_k( (Q[b,q]·K[b,k] + bias[b,q,k]) / 16 ) · vsum[b,k]
//   bias[b,i,j] = rn*(dot(D[b,i,j,:],gw) - mu*sum_gw) + bconst   (gw = g_p*(W_pt@W_ph))
//   vsum[b,k]   = Fn[b,k,:]·rowsum(Wv)
//
// Workspace layout (floats):
#define OFF_GW    0          // 64   : g_p * (W_pt @ W_ph)
#define OFF_WV    64         // 256  : row sums of Wv
#define OFF_SC    320        // 2    : sum_gw, bconst
#define OFF_VSUM  384        // 2048 : vsum[b,k]
#define OFF_Q     2432       // 524288 : Q [2048][256]
#define OFF_K     526720     // 524288 : K [2048][256]
// total ~4.2 MB of d_ws

typedef float v4f __attribute__((ext_vector_type(4)));

// ---------------- K0: constants -------------------------------------------
__global__ __launch_bounds__(256) void k0_consts(
    const float* __restrict__ Wv, const float* __restrict__ g_p,
    const float* __restrict__ b_p, const float* __restrict__ W_pt,
    const float* __restrict__ b_pt, const float* __restrict__ W_ph,
    float* __restrict__ ws) {
  int t = threadIdx.x;
  if (blockIdx.x < 64) {
    // wv_sum: 4 rows of Wv per block, one wave per row (coalesced)
    int row = blockIdx.x * 4 + (t >> 6);
    int l = t & 63;
    float s = 0.f;
#pragma unroll
    for (int j = 0; j < 4; ++j) s += Wv[row * 256 + l + 64 * j];
    for (int m = 32; m >= 1; m >>= 1) s += __shfl_xor(s, m);
    if (l == 0) ws[OFF_WV + row] = s;
  } else {
    __shared__ float wc_s[64];
    __shared__ float wph_s[128];
    if (t < 128) wph_s[t] = W_ph[t];
    __syncthreads();
    int c = t >> 2, sub = t & 3;  // 4 lanes per channel c
    float wc = 0.f;
#pragma unroll
    for (int j = 0; j < 32; ++j)
      wc += W_pt[c * 128 + sub * 32 + j] * wph_s[sub * 32 + j];
    wc += __shfl_xor(wc, 1);
    wc += __shfl_xor(wc, 2);
    if (sub == 0) {
      wc_s[c] = wc;
      ws[OFF_GW + c] = g_p[c] * wc;
    }
    __syncthreads();
    if (t == 0) {
      float sg = 0.f, bc = 0.f;
      for (int cc = 0; cc < 64; ++cc) {
        sg += g_p[cc] * wc_s[cc];
        bc += b_p[cc] * wc_s[cc];
      }
      for (int p = 0; p < 128; ++p) bc += b_pt[p] * wph_s[p];
      ws[OFF_SC] = sg;
      ws[OFF_SC + 1] = bc;
    }
  }
}

// ---------------- K1: LN(F) + Q,K projection + vsum ------------------------
// 512 blocks: rowgroup g = bid>>1 (8 rows), column half h = bid&1.
// Threads 0-127 -> Wq columns, 128-255 -> Wk columns.
// fn broadcast reads vectorized to ds_read_b128 (512/wave instead of 2048).
__global__ __launch_bounds__(256) void k1_ln_qk(
    const float* __restrict__ F, const float* __restrict__ Wq,
    const float* __restrict__ Wk, const float* __restrict__ g_f,
    const float* __restrict__ b_f, float* __restrict__ ws) {
  __shared__ __align__(16) float fn[8][260];  // 260: 16B-aligned row stride
  __shared__ float smu[8], srn[8];
  int t = threadIdx.x;
  int g = blockIdx.x >> 1, h = blockIdx.x & 1;
  int row0 = g * 8;  // global row in [0,2048)
  const float* Fp = F + (size_t)row0 * 256;
#pragma unroll
  for (int k = 0; k < 8; ++k) fn[k][t] = Fp[k * 256 + t];
  __syncthreads();
  // stats: 32 threads per row
  int r = t >> 5, l32 = t & 31;
  float s1 = 0.f, s2 = 0.f;
#pragma unroll
  for (int m = 0; m < 8; ++m) {
    float x = fn[r][l32 + 32 * m];
    s1 += x;
    s2 += x * x;
  }
  for (int m = 16; m >= 1; m >>= 1) {
    s1 += __shfl_xor(s1, m);
    s2 += __shfl_xor(s2, m);
  }
  if (l32 == 0) {
    float mu = s1 * (1.f / 256.f);
    float var = s2 * (1.f / 256.f) - mu * mu;
    smu[r] = mu;
    srn[r] = rsqrtf(var + 1e-3f);
  }
  __syncthreads();
  float gf = g_f[t], bf = b_f[t];
#pragma unroll
  for (int k = 0; k < 8; ++k)
    fn[k][t] = (fn[k][t] - smu[k]) * srn[k] * gf + bf;
  __syncthreads();
  if (h == 0) {  // vsum only once per row-group
    const float* wv = ws + OFF_WV;
    float s = 0.f;
#pragma unroll
    for (int m = 0; m < 8; ++m) s += fn[r][l32 + 32 * m] * wv[l32 + 32 * m];
    for (int m = 16; m >= 1; m >>= 1) s += __shfl_xor(s, m);
    if (l32 == 0) ws[OFF_VSUM + row0 + r] = s;
  }
  // projection: thread t -> matrix (t>>7), column h*128 + (t&127)
  int matsel = t >> 7;
  int col = h * 128 + (t & 127);
  const float* W = matsel ? Wk : Wq;
  float acc[8] = {0, 0, 0, 0, 0, 0, 0, 0};
#pragma unroll 2
  for (int f = 0; f < 256; f += 4) {
    float w0 = W[(f + 0) * 256 + col];
    float w1 = W[(f + 1) * 256 + col];
    float w2 = W[(f + 2) * 256 + col];
    float w3 = W[(f + 3) * 256 + col];
#pragma unroll
    for (int k = 0; k < 8; ++k) {
      v4f x = *(const v4f*)(&fn[k][f]);  // ds_read_b128 wave-uniform broadcast
      acc[k] = fmaf(x.w, w3,
               fmaf(x.z, w2, fmaf(x.y, w1, fmaf(x.x, w0, acc[k]))));
    }
  }
  float* Out = ws + (matsel ? OFF_K : OFF_Q) + (size_t)row0 * 256 + col;
#pragma unroll
  for (int k = 0; k < 8; ++k) Out[k * 256] = acc[k];
}

// ---------------- KB: fused pair-bias + QK^T + softmax + ·vsum -------------
// 512 blocks = (b, 4-q-row tile). Each block streams its own 512 KB of D
// (bias LN, nontemporal), adds QK^T/16, softmaxes per row, dots with vsum.
__global__ __launch_bounds__(256) void kb_bias_attn(
    const float* __restrict__ D, const float* __restrict__ ws,
    float* __restrict__ out) {
  __shared__ float4 Qs4[4][64];
  __shared__ float Sx[4][512];
  __shared__ float vs[512];
  int t = threadIdx.x;
  int b = blockIdx.x >> 7;      // 128 tiles per batch
  int tile = blockIdx.x & 127;
  int q0 = tile * 4;
  int rowbase = b * 512 + q0;   // global q row
  // stage Q rows + vsum
  float* qsf = (float*)Qs4;
#pragma unroll
  for (int k = 0; k < 4; ++k)
    qsf[k * 256 + t] = ws[OFF_Q + (size_t)(rowbase + k) * 256 + t];
  vs[t] = ws[OFF_VSUM + b * 512 + t];
  vs[t + 256] = ws[OFF_VSUM + b * 512 + 256 + t];
  float sum_gw = ws[OFF_SC];
  float bconst = ws[OFF_SC + 1];
  // this lane's quarter of gw (16 floats)
  int qq = t & 3;
  float4 g[4];
#pragma unroll
  for (int j = 0; j < 4; ++j) g[j] = ((const float4*)(ws + OFF_GW))[qq * 4 + j];

  // Phase A: bias for 4 q-rows x 512 k. 4 lanes per (q,k) entry; 32 passes.
  int e4 = t >> 2;  // 0..63
  const float* Dbase = D + (size_t)rowbase * 512 * 64;
#pragma unroll 4
  for (int pi = 0; pi < 32; ++pi) {
    int rr = pi >> 3;
    int kk = (pi & 7) * 64 + e4;
    const v4f* dp =
        (const v4f*)(Dbase + ((size_t)rr * 512 + kk) * 64 + qq * 16);
    float s1 = 0.f, s2 = 0.f, sw = 0.f;
#pragma unroll
    for (int j = 0; j < 4; ++j) {
      v4f x = __builtin_nontemporal_load(dp + j);  // one-touch stream
      s1 += x.x + x.y + x.z + x.w;
      s2 += x.x * x.x + x.y * x.y + x.z * x.z + x.w * x.w;
      sw += x.x * g[j].x + x.y * g[j].y + x.z * g[j].z + x.w * g[j].w;
    }
    s1 += __shfl_xor(s1, 1);
    s2 += __shfl_xor(s2, 1);
    sw += __shfl_xor(sw, 1);
    s1 += __shfl_xor(s1, 2);
    s2 += __shfl_xor(s2, 2);
    sw += __shfl_xor(sw, 2);
    if (qq == 0) {
      float mu = s1 * (1.f / 64.f);
      float var = s2 * (1.f / 64.f) - mu * mu;
      float rn = rsqrtf(var + 1e-3f);
      Sx[rr][kk] = (rn * (sw - mu * sum_gw) + bconst) * 0.0625f;
    }
  }
  __syncthreads();

  // Phase B: QK^T/16 added into Sx. Thread t owns k-cols t and t+256.
  const float* Kg = ws + OFF_K;
  const float4* K0p = (const float4*)(Kg + (size_t)(b * 512 + t) * 256);
  const float4* K1p = (const float4*)(Kg + (size_t)(b * 512 + 256 + t) * 256);
  float a0[4] = {0, 0, 0, 0}, a1[4] = {0, 0, 0, 0};
#pragma unroll 4
  for (int f = 0; f < 64; ++f) {
    float4 kv0 = K0p[f];
    float4 kv1 = K1p[f];
#pragma unroll
    for (int rr = 0; rr < 4; ++rr) {
      float4 qv = Qs4[rr][f];  // wave-uniform LDS broadcast
      a0[rr] += qv.x * kv0.x + qv.y * kv0.y + qv.z * kv0.z + qv.w * kv0.w;
      a1[rr] += qv.x * kv1.x + qv.y * kv1.y + qv.z * kv1.z + qv.w * kv1.w;
    }
  }
#pragma unroll
  for (int rr = 0; rr < 4; ++rr) {
    Sx[rr][t] += a0[rr] * 0.0625f;
    Sx[rr][t + 256] += a1[rr] * 0.0625f;
  }
  __syncthreads();

  // Phase C: wave w softmaxes row w and dots with vsum
  int w = t >> 6, l = t & 63;
  float m = -1e30f;
#pragma unroll
  for (int j = 0; j < 8; ++j) m = fmaxf(m, Sx[w][l + 64 * j]);
  for (int mm = 32; mm >= 1; mm >>= 1) m = fmaxf(m, __shfl_xor(m, mm));
  float se = 0.f, sv = 0.f;
#pragma unroll
  for (int j = 0; j < 8; ++j) {
    float ev = __expf(Sx[w][l + 64 * j] - m);
    se += ev;
    sv += ev * vs[l + 64 * j];
  }
  for (int mm = 32; mm >= 1; mm >>= 1) {
    se += __shfl_xor(se, mm);
    sv += __shfl_xor(sv, mm);
  }
  if (l == 0) out[rowbase + w] = sv / se;
}

// ---------------------------------------------------------------------------
extern "C" void kernel_launch(void* const* d_in, const int* in_sizes, int n_in,
                              void* d_out, int out_size, void* d_ws,
                              size_t ws_size, hipStream_t stream) {
  const float* F    = (const float*)d_in[0];
  const float* D    = (const float*)d_in[1];
  const float* Wq   = (const float*)d_in[2];
  const float* Wk   = (const float*)d_in[3];
  const float* Wv   = (const float*)d_in[4];
  const float* g_f  = (const float*)d_in[5];
  const float* b_f  = (const float*)d_in[6];
  const float* g_p  = (const float*)d_in[7];
  const float* b_p  = (const float*)d_in[8];
  const float* W_pt = (const float*)d_in[9];
  const float* b_pt = (const float*)d_in[10];
  const float* W_ph = (const float*)d_in[11];
  float* out = (float*)d_out;
  float* ws = (float*)d_ws;

  k0_consts<<<65, 256, 0, stream>>>(Wv, g_p, b_p, W_pt, b_pt, W_ph, ws);
  k1_ln_qk<<<512, 256, 0, stream>>>(F, Wq, Wk, g_f, b_f, ws);
  kb_bias_attn<<<512, 256, 0, stream>>>(D, ws, out);
}